// Round 1
// baseline (2578.356 us; speedup 1.0000x reference)
//
#include <hip/hip_runtime.h>
#include <stdint.h>

// FlashGPTJAttention on MI355X (gfx950).
// Pipeline: cvt fp32->bf16 -> QKV B^T-GEMM (scatter epilogue to q/k/v [b][h][s][d])
//   -> RoPE(q,k) -> V transpose [b][h][d][s] -> scores B^T-GEMM (causal tile skip,
//   fp32) -> row softmax (probs bf16 in-place in scores rows) -> PV B^T-GEMM
//   (K-loop capped at diagonal) -> out-proj B^T-GEMM (fp32 -> d_out).
// GEMM core mirrors the guide's m97 structure: 128x128 tile, BK=32, 4 waves,
// 4x4 x mfma_f32_16x16x32_bf16, global_load_lds width=16 staging.

typedef __bf16 bf16x8 __attribute__((ext_vector_type(8)));
typedef float f32x4 __attribute__((ext_vector_type(4)));

__device__ __forceinline__ unsigned short f2bf(float f) {
    union { float f; unsigned int u; } x;
    x.f = f;
    unsigned int r = x.u + 0x7fffu + ((x.u >> 16) & 1u);  // RNE
    return (unsigned short)(r >> 16);
}

__device__ __forceinline__ float bf2f(unsigned short h) {
    union { unsigned int u; float f; } x;
    x.u = ((unsigned int)h) << 16;
    return x.f;
}

__device__ __forceinline__ void gld16(const void* g, void* l) {
    __builtin_amdgcn_global_load_lds(
        (const __attribute__((address_space(1))) void*)g,
        (__attribute__((address_space(3))) void*)l, 16, 0, 0);
}

// ---------------------------------------------------------------------------
// fp32 -> bf16 convert, float4 loads / ushort4 stores, grid-stride
__global__ __launch_bounds__(256) void cvt_bf16(const float* __restrict__ src,
                                                unsigned short* __restrict__ dst,
                                                long n4) {
    long i = (long)blockIdx.x * 256 + threadIdx.x;
    long stride = (long)gridDim.x * 256;
    for (; i < n4; i += stride) {
        float4 v = ((const float4*)src)[i];
        ushort4 o;
        o.x = f2bf(v.x); o.y = f2bf(v.y); o.z = f2bf(v.z); o.w = f2bf(v.w);
        ((ushort4*)dst)[i] = o;
    }
}

// ---------------------------------------------------------------------------
// Templated B^T GEMM: C[m][n] = sum_k A[m][k] * B[n][k]  (both K-contiguous).
// EPI 0: QKV  -> scatter bf16 into q_s/k_s/v_s [B][16][1024][256]
// EPI 1: scores -> fp32 * 1/16 into scores[bz][m][n]; skip tiles above diagonal
// EPI 2: PV   -> bf16 into attn_out[token][h*256+d]; K-iters = (mtile+1)*4
// EPI 3: out-proj -> fp32 into d_out[m][n]
template <int EPI>
__global__ __launch_bounds__(256) void gemm_bt(
    const unsigned short* __restrict__ A, long astride, long abatch,
    const unsigned short* __restrict__ B, long bstride, long bbatch,
    int kIters, void* __restrict__ out,
    unsigned short* __restrict__ out2, unsigned short* __restrict__ out3) {
    const int tid = threadIdx.x;
    const int ntile = blockIdx.x, mtile = blockIdx.y, bz = blockIdx.z;
    if (EPI == 1 && ntile > mtile) return;  // causal: strictly-upper tiles
    int kit = kIters;
    if (EPI == 2) kit = (mtile + 1) * 4;    // causal cap: K up to diagonal tile

    __shared__ __attribute__((aligned(16))) unsigned short As[128 * 32];
    __shared__ __attribute__((aligned(16))) unsigned short Bs[128 * 32];

    const unsigned short* Ab = A + (long)bz * abatch + (long)mtile * 128 * astride;
    const unsigned short* Bb = B + (long)bz * bbatch + (long)ntile * 128 * bstride;

    const int w = tid >> 6, l = tid & 63;
    const int wm = (w >> 1) * 64, wn = (w & 1) * 64;
    const int lr = l & 15, lk = (l >> 4) * 8;

    // staging: chunk c covers row c>>2, 8-elem k-chunk c&3 (16B per lane)
    const int c0 = tid, c1 = tid + 256;
    const long a0 = (long)(c0 >> 2) * astride + (c0 & 3) * 8;
    const long a1 = (long)(c1 >> 2) * astride + (c1 & 3) * 8;
    const long b0 = (long)(c0 >> 2) * bstride + (c0 & 3) * 8;
    const long b1 = (long)(c1 >> 2) * bstride + (c1 & 3) * 8;

    f32x4 acc[4][4];
#pragma unroll
    for (int i = 0; i < 4; ++i)
#pragma unroll
        for (int j = 0; j < 4; ++j) acc[i][j] = (f32x4)(0.0f);

    for (int kt = 0; kt < kit; ++kt) {
        const unsigned short* ak = Ab + kt * 32;
        const unsigned short* bk = Bb + kt * 32;
        __syncthreads();  // protect LDS from prior iteration's readers
        gld16(ak + a0, As + (long)c0 * 8);
        gld16(ak + a1, As + (long)c1 * 8);
        gld16(bk + b0, Bs + (long)c0 * 8);
        gld16(bk + b1, Bs + (long)c1 * 8);
        __syncthreads();  // drains vmcnt before barrier (compiler-inserted)

        bf16x8 af[4], bf[4];
#pragma unroll
        for (int i = 0; i < 4; ++i) {
            af[i] = *(const bf16x8*)(As + (wm + i * 16 + lr) * 32 + lk);
            bf[i] = *(const bf16x8*)(Bs + (wn + i * 16 + lr) * 32 + lk);
        }
#pragma unroll
        for (int mi = 0; mi < 4; ++mi)
#pragma unroll
            for (int ni = 0; ni < 4; ++ni)
                acc[mi][ni] = __builtin_amdgcn_mfma_f32_16x16x32_bf16(
                    af[mi], bf[ni], acc[mi][ni], 0, 0, 0);
    }

    // epilogue: C/D layout col = lane&15, row = (lane>>4)*4 + reg  [m89-verified]
    const int mBase = mtile * 128 + wm + (l >> 4) * 4;
    const int nBase = ntile * 128 + wn + (l & 15);
#pragma unroll
    for (int mi = 0; mi < 4; ++mi) {
#pragma unroll
        for (int ni = 0; ni < 4; ++ni) {
#pragma unroll
            for (int r = 0; r < 4; ++r) {
                const int m = mBase + mi * 16 + r;
                const int n = nBase + ni * 16;
                const float v = acc[mi][ni][r];
                if (EPI == 0) {
                    const int which = n >> 12, h = (n >> 8) & 15, d = n & 255;
                    const int b = m >> 10, s = m & 1023;
                    const long idx = ((((long)b * 16 + h) << 10) + s) * 256 + d;
                    unsigned short* dst =
                        (which == 0) ? (unsigned short*)out : (which == 1 ? out2 : out3);
                    dst[idx] = f2bf(v);
                } else if (EPI == 1) {
                    ((float*)out)[((long)bz << 20) + ((long)m << 10) + n] = v * 0.0625f;
                } else if (EPI == 2) {
                    const int b = bz >> 4, h = bz & 15;
                    ((unsigned short*)out)[(((long)b << 10) + m) * 4096 + h * 256 + n] =
                        f2bf(v);
                } else {
                    ((float*)out)[((long)m << 12) + n] = v;
                }
            }
        }
    }
}

// ---------------------------------------------------------------------------
// RoPE (GPT-NeoX rotate-half, rotary_dim=64) applied in place to q_s and k_s.
// One thread per (token, head, pair i<32); reads both halves then writes both.
__global__ __launch_bounds__(256) void rope_qk(unsigned short* __restrict__ q_s,
                                               unsigned short* __restrict__ k_s,
                                               const float* __restrict__ cosp,
                                               const float* __restrict__ sinp) {
    const int tid = blockIdx.x * 256 + threadIdx.x;  // 8192*16*32 total
    const int i = tid & 31;
    const int h = (tid >> 5) & 15;
    const int tok = tid >> 9;
    const int b = tok >> 10, s = tok & 1023;
    const long base = ((((long)b * 16 + h) << 10) + s) * 256 + i;
    const float c = cosp[tok * 32 + i];
    const float sn = sinp[tok * 32 + i];
    {
        float x1 = bf2f(q_s[base]), x2 = bf2f(q_s[base + 32]);
        q_s[base] = f2bf(x1 * c - x2 * sn);
        q_s[base + 32] = f2bf(x2 * c + x1 * sn);
    }
    {
        float x1 = bf2f(k_s[base]), x2 = bf2f(k_s[base + 32]);
        k_s[base] = f2bf(x1 * c - x2 * sn);
        k_s[base + 32] = f2bf(x2 * c + x1 * sn);
    }
}

// ---------------------------------------------------------------------------
// V transpose per (b,h): [s][d] -> [d][s], 32x32 LDS tiles.
__global__ __launch_bounds__(256) void vtrans(const unsigned short* __restrict__ v_s,
                                              unsigned short* __restrict__ vT) {
    __shared__ unsigned short tile[32][33];
    const int bh = blockIdx.z;
    const int s0 = blockIdx.x * 32, d0 = blockIdx.y * 32;
    const int x = threadIdx.x, y = threadIdx.y;  // 32 x 8
    const unsigned short* src = v_s + (((long)bh << 10) + s0) * 256 + d0;
#pragma unroll
    for (int j = 0; j < 4; ++j) tile[y * 4 + j][x] = src[(y * 4 + j) * 256 + x];
    __syncthreads();
    unsigned short* dst = vT + (((long)bh << 8) + d0) * 1024 + s0;
#pragma unroll
    for (int j = 0; j < 4; ++j) dst[(y * 4 + j) * 1024 + x] = tile[x][y * 4 + j];
}

// ---------------------------------------------------------------------------
// Causal row softmax over scores[bh][q][0..q]; writes bf16 probs in place into
// the row's own fp32 span (first 2KB of the 4KB row): probs row stride = 2048
// bf16 elems. Zeros written for q < k < row's diagonal-tile end so the PV GEMM
// (which reads whole 128-wide K tiles) sees exact zeros.
__global__ __launch_bounds__(256) void softmax_rows(float* __restrict__ scores) {
    const int row = blockIdx.x;           // 128*1024 rows
    const int bh = row >> 10, q = row & 1023;
    float* srow = scores + ((long)bh << 20) + ((long)q << 10);
    const int t = threadIdx.x;

    float v[4];
#pragma unroll
    for (int j = 0; j < 4; ++j) {
        const int k = t + (j << 8);
        v[j] = (k <= q) ? srow[k] : -3.0e38f;
    }
    float mx = fmaxf(fmaxf(v[0], v[1]), fmaxf(v[2], v[3]));
#pragma unroll
    for (int off = 32; off >= 1; off >>= 1) mx = fmaxf(mx, __shfl_xor(mx, off));
    __shared__ float redmax[4];
    if ((t & 63) == 0) redmax[t >> 6] = mx;
    __syncthreads();  // also orders all scores loads before any probs store
    mx = fmaxf(fmaxf(redmax[0], redmax[1]), fmaxf(redmax[2], redmax[3]));

    float p[4];
    float s = 0.0f;
#pragma unroll
    for (int j = 0; j < 4; ++j) {
        const int k = t + (j << 8);
        p[j] = (k <= q) ? __expf(v[j] - mx) : 0.0f;
        s += p[j];
    }
#pragma unroll
    for (int off = 32; off >= 1; off >>= 1) s += __shfl_xor(s, off);
    __shared__ float redsum[4];
    if ((t & 63) == 0) redsum[t >> 6] = s;
    __syncthreads();
    s = redsum[0] + redsum[1] + redsum[2] + redsum[3];
    const float inv = 1.0f / s;

    unsigned short* prow = (unsigned short*)srow;
    const int kend = (q & ~127) + 128;  // diagonal-tile end
#pragma unroll
    for (int j = 0; j < 4; ++j) {
        const int k = t + (j << 8);
        if (k < kend) prow[k] = f2bf(p[j] * inv);
    }
}

// ---------------------------------------------------------------------------
extern "C" void kernel_launch(void* const* d_in, const int* in_sizes, int n_in,
                              void* d_out, int out_size, void* d_ws, size_t ws_size,
                              hipStream_t stream) {
    const float* hidden = (const float*)d_in[0];  // [8192][4096]
    const float* w_qkv  = (const float*)d_in[1];  // [12288][4096]
    const float* w_o    = (const float*)d_in[2];  // [4096][4096]
    const float* cosp   = (const float*)d_in[3];  // [8192][32]
    const float* sinp   = (const float*)d_in[4];  // [8192][32]
    // d_in[5..7]: key_cache / value_cache / slots — identity scatter+gather,
    // no effect on the returned output; skipped.

    // workspace layout (bytes); scores region aliases hidden_bf16+wqkv_bf16
    // (dead after the QKV GEMM). Total = 905,969,664.
    const long SZ_WO = 33554432L, SZ_HEAD = 67108864L, SZ_SCORES = 536870912L;
    if (ws_size < (size_t)(SZ_WO + 5 * SZ_HEAD + SZ_SCORES)) return;  // clean no-op fail
    char* p = (char*)d_ws;
    unsigned short* wo_b = (unsigned short*)p;  p += SZ_WO;
    unsigned short* q_s  = (unsigned short*)p;  p += SZ_HEAD;
    unsigned short* k_s  = (unsigned short*)p;  p += SZ_HEAD;
    unsigned short* v_s  = (unsigned short*)p;  p += SZ_HEAD;
    unsigned short* vT   = (unsigned short*)p;  p += SZ_HEAD;
    unsigned short* attn = (unsigned short*)p;  p += SZ_HEAD;
    char* X = p;
    unsigned short* hid_b  = (unsigned short*)X;
    unsigned short* wqkv_b = (unsigned short*)(X + SZ_HEAD);
    float* scores = (float*)X;

    // 1) converts
    cvt_bf16<<<8192, 256, 0, stream>>>(hidden, hid_b, (long)8192 * 4096 / 4);
    cvt_bf16<<<8192, 256, 0, stream>>>(w_qkv, wqkv_b, (long)12288 * 4096 / 4);
    cvt_bf16<<<4096, 256, 0, stream>>>(w_o, wo_b, (long)4096 * 4096 / 4);

    // 2) QKV GEMM: M=8192, N=12288, K=4096
    gemm_bt<0><<<dim3(96, 64, 1), 256, 0, stream>>>(
        hid_b, 4096, 0, wqkv_b, 4096, 0, 128, q_s, k_s, v_s);

    // 3) RoPE on q,k
    rope_qk<<<16384, 256, 0, stream>>>(q_s, k_s, cosp, sinp);

    // 4) V transpose -> vT [bh][256][1024]
    vtrans<<<dim3(32, 8, 128), dim3(32, 8, 1), 0, stream>>>(v_s, vT);

    // 5) scores = q k^T / 16 per (b,h): M=N=1024, K=256, causal tile skip
    gemm_bt<1><<<dim3(8, 8, 128), 256, 0, stream>>>(
        q_s, 256, 262144, k_s, 256, 262144, 8, scores, nullptr, nullptr);

    // 6) softmax (in-place probs, bf16, row stride 2048 elems)
    softmax_rows<<<131072, 256, 0, stream>>>(scores);

    // 7) PV: A=probs (stride 2048, batch 1024*2048), B^T=vT, N=256
    gemm_bt<2><<<dim3(2, 8, 128), 256, 0, stream>>>(
        (unsigned short*)scores, 2048, 2097152, vT, 1024, 262144, 0,
        attn, nullptr, nullptr);

    // 8) out-proj: M=8192, N=4096, K=4096 -> fp32 d_out
    gemm_bt<3><<<dim3(32, 64, 1), 256, 0, stream>>>(
        attn, 4096, 0, wo_b, 4096, 0, 128, d_out, nullptr, nullptr);

    (void)in_sizes; (void)n_in; (void)out_size;
}

// Round 2
// 2527.097 us; speedup vs baseline: 1.0203x; 1.0203x over previous
//
#include <hip/hip_runtime.h>
#include <stdint.h>

// FlashGPTJAttention on MI355X (gfx950).
// Pipeline: cvt fp32->bf16 -> QKV B^T-GEMM (scatter epilogue to q/k/v [b][h][s][d])
//   -> RoPE(q,k) -> V transpose [b][h][d][s] -> scores B^T-GEMM (causal tile skip,
//   fp32) -> row softmax (probs bf16 in-place in scores rows) -> PV B^T-GEMM
//   (K-loop capped at diagonal) -> out-proj B^T-GEMM (fp32 -> d_out).
// GEMM core: m97 structure (128x128 tile, BK=32, 4 waves, 4x4 mfma 16x16x32 bf16,
// global_load_lds width=16) + R1 fix: XOR chunk swizzle to kill the 8-way LDS
// bank conflict (1.0e8 SQ_LDS_BANK_CONFLICT measured with linear layout).
// Swizzle: logical 16B chunk c of row r lives at physical chunk c ^ ((r>>1)&3).
// global_load_lds forces linear lane->LDS placement, so the inverse swizzle is
// applied to the GLOBAL source address at staging time.

typedef __bf16 bf16x8 __attribute__((ext_vector_type(8)));
typedef float f32x4 __attribute__((ext_vector_type(4)));

__device__ __forceinline__ unsigned short f2bf(float f) {
    union { float f; unsigned int u; } x;
    x.f = f;
    unsigned int r = x.u + 0x7fffu + ((x.u >> 16) & 1u);  // RNE
    return (unsigned short)(r >> 16);
}

__device__ __forceinline__ float bf2f(unsigned short h) {
    union { unsigned int u; float f; } x;
    x.u = ((unsigned int)h) << 16;
    return x.f;
}

__device__ __forceinline__ void gld16(const void* g, void* l) {
    __builtin_amdgcn_global_load_lds(
        (const __attribute__((address_space(1))) void*)g,
        (__attribute__((address_space(3))) void*)l, 16, 0, 0);
}

// ---------------------------------------------------------------------------
// fp32 -> bf16 convert, float4 loads / ushort4 stores, grid-stride
__global__ __launch_bounds__(256) void cvt_bf16(const float* __restrict__ src,
                                                unsigned short* __restrict__ dst,
                                                long n4) {
    long i = (long)blockIdx.x * 256 + threadIdx.x;
    long stride = (long)gridDim.x * 256;
    for (; i < n4; i += stride) {
        float4 v = ((const float4*)src)[i];
        ushort4 o;
        o.x = f2bf(v.x); o.y = f2bf(v.y); o.z = f2bf(v.z); o.w = f2bf(v.w);
        ((ushort4*)dst)[i] = o;
    }
}

// ---------------------------------------------------------------------------
// Templated B^T GEMM: C[m][n] = sum_k A[m][k] * B[n][k]  (both K-contiguous).
// EPI 0: QKV  -> scatter bf16 into q_s/k_s/v_s [B][16][1024][256]
// EPI 1: scores -> fp32 * 1/16 into scores[bz][m][n]; skip tiles above diagonal
// EPI 2: PV   -> bf16 into attn_out[token][h*256+d]; K-iters = (mtile+1)*4
// EPI 3: out-proj -> fp32 into d_out[m][n]
template <int EPI>
__global__ __launch_bounds__(256) void gemm_bt(
    const unsigned short* __restrict__ A, long astride, long abatch,
    const unsigned short* __restrict__ B, long bstride, long bbatch,
    int kIters, void* __restrict__ out,
    unsigned short* __restrict__ out2, unsigned short* __restrict__ out3) {
    const int tid = threadIdx.x;
    const int ntile = blockIdx.x, mtile = blockIdx.y, bz = blockIdx.z;
    if (EPI == 1 && ntile > mtile) return;  // causal: strictly-upper tiles
    int kit = kIters;
    if (EPI == 2) kit = (mtile + 1) * 4;    // causal cap: K up to diagonal tile

    __shared__ __attribute__((aligned(16))) unsigned short As[128 * 32];
    __shared__ __attribute__((aligned(16))) unsigned short Bs[128 * 32];

    const unsigned short* Ab = A + (long)bz * abatch + (long)mtile * 128 * astride;
    const unsigned short* Bb = B + (long)bz * bbatch + (long)ntile * 128 * bstride;

    const int w = tid >> 6, l = tid & 63;
    const int wm = (w >> 1) * 64, wn = (w & 1) * 64;
    const int lr = l & 15;
    const int lc = l >> 4;  // logical 16B k-chunk this lane's fragment starts at

    // staging: physical chunk p = row p>>2, physical chunk-in-row p&3. The data
    // that belongs there is logical chunk (p&3) ^ ((row>>1)&3)  (inverse swizzle
    // applied to the global address; LDS placement is the forced linear one).
    const int c0 = tid, c1 = tid + 256;
    const int r0 = c0 >> 2, r1 = c1 >> 2;
    const int lc0 = (c0 & 3) ^ ((r0 >> 1) & 3);
    const int lc1 = (c1 & 3) ^ ((r1 >> 1) & 3);
    const long a0 = (long)r0 * astride + lc0 * 8;
    const long a1 = (long)r1 * astride + lc1 * 8;
    const long b0 = (long)r0 * bstride + lc0 * 8;
    const long b1 = (long)r1 * bstride + lc1 * 8;

    // fragment read offsets (elements), forward swizzle per row
    int aoff[4], boff[4];
#pragma unroll
    for (int i = 0; i < 4; ++i) {
        const int ra = wm + i * 16 + lr;
        aoff[i] = ra * 32 + ((lc ^ ((ra >> 1) & 3)) << 3);
        const int rb = wn + i * 16 + lr;
        boff[i] = rb * 32 + ((lc ^ ((rb >> 1) & 3)) << 3);
    }

    f32x4 acc[4][4];
#pragma unroll
    for (int i = 0; i < 4; ++i)
#pragma unroll
        for (int j = 0; j < 4; ++j) acc[i][j] = (f32x4)(0.0f);

    for (int kt = 0; kt < kit; ++kt) {
        const unsigned short* ak = Ab + kt * 32;
        const unsigned short* bk = Bb + kt * 32;
        __syncthreads();  // protect LDS from prior iteration's readers
        gld16(ak + a0, As + (long)c0 * 8);
        gld16(ak + a1, As + (long)c1 * 8);
        gld16(bk + b0, Bs + (long)c0 * 8);
        gld16(bk + b1, Bs + (long)c1 * 8);
        __syncthreads();  // drains vmcnt before barrier (compiler-inserted)

        bf16x8 af[4], bf[4];
#pragma unroll
        for (int i = 0; i < 4; ++i) {
            af[i] = *(const bf16x8*)(As + aoff[i]);
            bf[i] = *(const bf16x8*)(Bs + boff[i]);
        }
#pragma unroll
        for (int mi = 0; mi < 4; ++mi)
#pragma unroll
            for (int ni = 0; ni < 4; ++ni)
                acc[mi][ni] = __builtin_amdgcn_mfma_f32_16x16x32_bf16(
                    af[mi], bf[ni], acc[mi][ni], 0, 0, 0);
    }

    // epilogue: C/D layout col = lane&15, row = (lane>>4)*4 + reg  [m89-verified]
    const int mBase = mtile * 128 + wm + (l >> 4) * 4;
    const int nBase = ntile * 128 + wn + (l & 15);
#pragma unroll
    for (int mi = 0; mi < 4; ++mi) {
#pragma unroll
        for (int ni = 0; ni < 4; ++ni) {
#pragma unroll
            for (int r = 0; r < 4; ++r) {
                const int m = mBase + mi * 16 + r;
                const int n = nBase + ni * 16;
                const float v = acc[mi][ni][r];
                if (EPI == 0) {
                    const int which = n >> 12, h = (n >> 8) & 15, d = n & 255;
                    const int b = m >> 10, s = m & 1023;
                    const long idx = ((((long)b * 16 + h) << 10) + s) * 256 + d;
                    unsigned short* dst =
                        (which == 0) ? (unsigned short*)out : (which == 1 ? out2 : out3);
                    dst[idx] = f2bf(v);
                } else if (EPI == 1) {
                    ((float*)out)[((long)bz << 20) + ((long)m << 10) + n] = v * 0.0625f;
                } else if (EPI == 2) {
                    const int b = bz >> 4, h = bz & 15;
                    ((unsigned short*)out)[(((long)b << 10) + m) * 4096 + h * 256 + n] =
                        f2bf(v);
                } else {
                    ((float*)out)[((long)m << 12) + n] = v;
                }
            }
        }
    }
}

// ---------------------------------------------------------------------------
// RoPE (GPT-NeoX rotate-half, rotary_dim=64) applied in place to q_s and k_s.
__global__ __launch_bounds__(256) void rope_qk(unsigned short* __restrict__ q_s,
                                               unsigned short* __restrict__ k_s,
                                               const float* __restrict__ cosp,
                                               const float* __restrict__ sinp) {
    const int tid = blockIdx.x * 256 + threadIdx.x;  // 8192*16*32 total
    const int i = tid & 31;
    const int h = (tid >> 5) & 15;
    const int tok = tid >> 9;
    const int b = tok >> 10, s = tok & 1023;
    const long base = ((((long)b * 16 + h) << 10) + s) * 256 + i;
    const float c = cosp[tok * 32 + i];
    const float sn = sinp[tok * 32 + i];
    {
        float x1 = bf2f(q_s[base]), x2 = bf2f(q_s[base + 32]);
        q_s[base] = f2bf(x1 * c - x2 * sn);
        q_s[base + 32] = f2bf(x2 * c + x1 * sn);
    }
    {
        float x1 = bf2f(k_s[base]), x2 = bf2f(k_s[base + 32]);
        k_s[base] = f2bf(x1 * c - x2 * sn);
        k_s[base + 32] = f2bf(x2 * c + x1 * sn);
    }
}

// ---------------------------------------------------------------------------
// V transpose per (b,h): [s][d] -> [d][s], 32x32 LDS tiles.
__global__ __launch_bounds__(256) void vtrans(const unsigned short* __restrict__ v_s,
                                              unsigned short* __restrict__ vT) {
    __shared__ unsigned short tile[32][33];
    const int bh = blockIdx.z;
    const int s0 = blockIdx.x * 32, d0 = blockIdx.y * 32;
    const int x = threadIdx.x, y = threadIdx.y;  // 32 x 8
    const unsigned short* src = v_s + (((long)bh << 10) + s0) * 256 + d0;
#pragma unroll
    for (int j = 0; j < 4; ++j) tile[y * 4 + j][x] = src[(y * 4 + j) * 256 + x];
    __syncthreads();
    unsigned short* dst = vT + (((long)bh << 8) + d0) * 1024 + s0;
#pragma unroll
    for (int j = 0; j < 4; ++j) dst[(y * 4 + j) * 1024 + x] = tile[x][y * 4 + j];
}

// ---------------------------------------------------------------------------
// Causal row softmax over scores[bh][q][0..q]; writes bf16 probs in place into
// the row's own fp32 span: probs row stride = 2048 bf16 elems. Zeros written
// for q < k < diagonal-tile end so the PV GEMM sees exact zeros.
__global__ __launch_bounds__(256) void softmax_rows(float* __restrict__ scores) {
    const int row = blockIdx.x;           // 128*1024 rows
    const int bh = row >> 10, q = row & 1023;
    float* srow = scores + ((long)bh << 20) + ((long)q << 10);
    const int t = threadIdx.x;

    float v[4];
#pragma unroll
    for (int j = 0; j < 4; ++j) {
        const int k = t + (j << 8);
        v[j] = (k <= q) ? srow[k] : -3.0e38f;
    }
    float mx = fmaxf(fmaxf(v[0], v[1]), fmaxf(v[2], v[3]));
#pragma unroll
    for (int off = 32; off >= 1; off >>= 1) mx = fmaxf(mx, __shfl_xor(mx, off));
    __shared__ float redmax[4];
    if ((t & 63) == 0) redmax[t >> 6] = mx;
    __syncthreads();  // also orders all scores loads before any probs store
    mx = fmaxf(fmaxf(redmax[0], redmax[1]), fmaxf(redmax[2], redmax[3]));

    float p[4];
    float s = 0.0f;
#pragma unroll
    for (int j = 0; j < 4; ++j) {
        const int k = t + (j << 8);
        p[j] = (k <= q) ? __expf(v[j] - mx) : 0.0f;
        s += p[j];
    }
#pragma unroll
    for (int off = 32; off >= 1; off >>= 1) s += __shfl_xor(s, off);
    __shared__ float redsum[4];
    if ((t & 63) == 0) redsum[t >> 6] = s;
    __syncthreads();
    s = redsum[0] + redsum[1] + redsum[2] + redsum[3];
    const float inv = 1.0f / s;

    unsigned short* prow = (unsigned short*)srow;
    const int kend = (q & ~127) + 128;  // diagonal-tile end
#pragma unroll
    for (int j = 0; j < 4; ++j) {
        const int k = t + (j << 8);
        if (k < kend) prow[k] = f2bf(p[j] * inv);
    }
}

// ---------------------------------------------------------------------------
extern "C" void kernel_launch(void* const* d_in, const int* in_sizes, int n_in,
                              void* d_out, int out_size, void* d_ws, size_t ws_size,
                              hipStream_t stream) {
    const float* hidden = (const float*)d_in[0];  // [8192][4096]
    const float* w_qkv  = (const float*)d_in[1];  // [12288][4096]
    const float* w_o    = (const float*)d_in[2];  // [4096][4096]
    const float* cosp   = (const float*)d_in[3];  // [8192][32]
    const float* sinp   = (const float*)d_in[4];  // [8192][32]
    // d_in[5..7]: key_cache / value_cache / slots — identity scatter+gather,
    // no effect on the returned output; skipped.

    // workspace layout (bytes); scores region aliases hidden_bf16+wqkv_bf16
    // (dead after the QKV GEMM). Total = 905,969,664.
    const long SZ_WO = 33554432L, SZ_HEAD = 67108864L, SZ_SCORES = 536870912L;
    if (ws_size < (size_t)(SZ_WO + 5 * SZ_HEAD + SZ_SCORES)) return;  // clean no-op fail
    char* p = (char*)d_ws;
    unsigned short* wo_b = (unsigned short*)p;  p += SZ_WO;
    unsigned short* q_s  = (unsigned short*)p;  p += SZ_HEAD;
    unsigned short* k_s  = (unsigned short*)p;  p += SZ_HEAD;
    unsigned short* v_s  = (unsigned short*)p;  p += SZ_HEAD;
    unsigned short* vT   = (unsigned short*)p;  p += SZ_HEAD;
    unsigned short* attn = (unsigned short*)p;  p += SZ_HEAD;
    char* X = p;
    unsigned short* hid_b  = (unsigned short*)X;
    unsigned short* wqkv_b = (unsigned short*)(X + SZ_HEAD);
    float* scores = (float*)X;

    // 1) converts
    cvt_bf16<<<8192, 256, 0, stream>>>(hidden, hid_b, (long)8192 * 4096 / 4);
    cvt_bf16<<<8192, 256, 0, stream>>>(w_qkv, wqkv_b, (long)12288 * 4096 / 4);
    cvt_bf16<<<4096, 256, 0, stream>>>(w_o, wo_b, (long)4096 * 4096 / 4);

    // 2) QKV GEMM: M=8192, N=12288, K=4096
    gemm_bt<0><<<dim3(96, 64, 1), 256, 0, stream>>>(
        hid_b, 4096, 0, wqkv_b, 4096, 0, 128, q_s, k_s, v_s);

    // 3) RoPE on q,k
    rope_qk<<<16384, 256, 0, stream>>>(q_s, k_s, cosp, sinp);

    // 4) V transpose -> vT [bh][256][1024]
    vtrans<<<dim3(32, 8, 128), dim3(32, 8, 1), 0, stream>>>(v_s, vT);

    // 5) scores = q k^T / 16 per (b,h): M=N=1024, K=256, causal tile skip
    gemm_bt<1><<<dim3(8, 8, 128), 256, 0, stream>>>(
        q_s, 256, 262144, k_s, 256, 262144, 8, scores, nullptr, nullptr);

    // 6) softmax (in-place probs, bf16, row stride 2048 elems)
    softmax_rows<<<131072, 256, 0, stream>>>(scores);

    // 7) PV: A=probs (stride 2048, batch 1024*2048), B^T=vT, N=256
    gemm_bt<2><<<dim3(2, 8, 128), 256, 0, stream>>>(
        (unsigned short*)scores, 2048, 2097152, vT, 1024, 262144, 0,
        attn, nullptr, nullptr);

    // 8) out-proj: M=8192, N=4096, K=4096 -> fp32 d_out
    gemm_bt<3><<<dim3(32, 64, 1), 256, 0, stream>>>(
        attn, 4096, 0, wo_b, 4096, 0, 128, d_out, nullptr, nullptr);

    (void)in_sizes; (void)n_in; (void)out_size;
}